// Round 11
// baseline (618.034 us; speedup 1.0000x reference)
//
#include <hip/hip_runtime.h>
#include <math.h>

typedef unsigned short u16;
typedef __attribute__((ext_vector_type(8))) short short8;
typedef __attribute__((ext_vector_type(4))) float f32x4;

#define Bb 256
#define Rr 6
#define Ksp 49
#define Cc 512
#define Hh 1024
#define Ee 300
#define NN (Bb*Rr)        // 1536
#define NLl 2001

__device__ __forceinline__ u16 f2b(float x) {
    union { float f; unsigned u; } c; c.f = x;
    unsigned r = c.u + 0x7fffu + ((c.u >> 16) & 1u);   // RNE, finite inputs
    return (u16)(r >> 16);
}
__device__ __forceinline__ float b2f(u16 b) {
    union { unsigned u; float f; } c; c.u = ((unsigned)b) << 16; return c.f;
}

// async global->LDS, 16B per lane; LDS dest = wave-uniform base + lane*16
#define ASYNC16(gp, lp) __builtin_amdgcn_global_load_lds( \
    (const __attribute__((address_space(1))) unsigned int*)(gp), \
    (__attribute__((address_space(3))) unsigned int*)(lp), 16, 0, 0)

// ---- weight-pool element offsets (bf16 B^T buffers) ----
constexpr size_t O_QC   = 0;                            // [1024][640]
constexpr size_t O_UQCB = O_QC   + (size_t)1024*640;    // [1024][640] (uqc rows 1024..1623 ^T)
constexpr size_t O_AV   = O_UQCB + (size_t)1024*640;    // [1024][512]
constexpr size_t O_AQQN = O_AV   + (size_t)1024*512;    // [2048][1024]
constexpr size_t O_VN   = O_AQQN + (size_t)2048*1024;   // [1024][512]
constexpr size_t O_QKV  = O_VN   + (size_t)1024*512;    // [3072][1024] = Wq^T | Wk^T | WvWo^T
constexpr size_t O_WO   = O_QKV  + (size_t)3072*1024;   // [1024][1024] Wo^T
constexpr size_t O_UQCT = O_WO   + (size_t)1024*1024;   // [1024][1024] (uqc rows 0..1023 ^T)
constexpr size_t O_CLS  = O_UQCT + (size_t)1024*1024;   // [2048][1024]
constexpr size_t O_WVP  = O_CLS  + (size_t)2048*1024;   // [1024][1024] Wv plain bf16
constexpr size_t WT_ELEMS = O_WVP + (size_t)2048*1024;

// ---------------- small/medium bf16 MFMA GEMM, LDS dbuf -------------------
// TAG = instrumentation-only. A bf16 [..][lda], Bt bf16 [N][K], K % BK == 0.
// Optional fp32 addend Cadd. col<split -> Cb bf16; col>=split -> Cf fp32.
// act bit0 = relu on bf16 half, bit1 = relu on fp32 half.
template<int TAG, int BM, int BN, int BK>
__global__ void __launch_bounds__(256) gemm_bf16(
    const u16* __restrict__ A, int lda, const u16* __restrict__ Bt,
    const float* __restrict__ bias, const float* __restrict__ Cadd, int ldadd,
    u16* __restrict__ Cb, int ldcb, float* __restrict__ Cf, int ldcf,
    int K, int split, int Nreal, int act)
{
    constexpr int SM = BM / 16, SN = BN / 16;
    constexpr int KG = BK / 32;
    constexpr int WM = BM / 32, WN = BN / 32;
    constexpr int BUF = (SM + SN) * KG * 512;
    __shared__ u16 lds[2 * BUF];
    const int tid  = threadIdx.x;
    const int wave = tid >> 6, lane = tid & 63;
    const int m0 = lane & 15, q0 = lane >> 4;

    const int gn = gridDim.x;
    const int nblk = gn * gridDim.y;
    const int lid = blockIdx.y * gn + blockIdx.x;
    const int per = nblk >> 3, rem = nblk & 7;
    const int xcd = lid & 7, slot = lid >> 3;
    const int t = xcd * per + ((xcd < rem) ? xcd : rem) + slot;
    const int tm = t / gn, tn = t - tm * gn;
    const int bm = tm * BM, bn = tn * BN;
    const int wr = wave >> 1, wc = wave & 1;

    auto stage = [&](int kt, int buf) {
        u16* l = &lds[buf * BUF];
        #pragma unroll
        for (int s = wave; s < SM; s += 4)
            #pragma unroll
            for (int g = 0; g < KG; g++) {
                const u16* gp = A + (size_t)(bm + s * 16 + m0) * lda + kt + g * 32 + q0 * 8;
                ASYNC16(gp, &l[(s * KG + g) * 512]);
            }
        #pragma unroll
        for (int s = wave; s < SN; s += 4)
            #pragma unroll
            for (int g = 0; g < KG; g++) {
                const u16* gp = Bt + (size_t)(bn + s * 16 + m0) * K + kt + g * 32 + q0 * 8;
                ASYNC16(gp, &l[(SM * KG + s * KG + g) * 512]);
            }
    };

    f32x4 acc[WM][WN];
    #pragma unroll
    for (int i = 0; i < WM; i++)
        #pragma unroll
        for (int j = 0; j < WN; j++)
            acc[i][j] = (f32x4){0.f, 0.f, 0.f, 0.f};

    stage(0, 0);
    const int nIter = K / BK;
    for (int it = 0; it < nIter; ++it) {
        __syncthreads();
        if (it + 1 < nIter) stage((it + 1) * BK, (it + 1) & 1);
        const u16* l = &lds[(it & 1) * BUF];
        short8 af[WM][KG], bf[WN][KG];
        #pragma unroll
        for (int i = 0; i < WM; i++)
            #pragma unroll
            for (int g = 0; g < KG; g++)
                af[i][g] = *(const short8*)&l[(((wr * WM + i) * KG + g) * 64 + lane) * 8];
        #pragma unroll
        for (int j = 0; j < WN; j++)
            #pragma unroll
            for (int g = 0; g < KG; g++)
                bf[j][g] = *(const short8*)&l[((SM * KG + (wc * WN + j) * KG + g) * 64 + lane) * 8];
        #pragma unroll
        for (int g = 0; g < KG; g++)
            #pragma unroll
            for (int i = 0; i < WM; i++)
                #pragma unroll
                for (int j = 0; j < WN; j++)
                    acc[i][j] = __builtin_amdgcn_mfma_f32_16x16x32_bf16(
                        af[i][g], bf[j][g], acc[i][j], 0, 0, 0);
    }

    #pragma unroll
    for (int i = 0; i < WM; i++) {
        #pragma unroll
        for (int j = 0; j < WN; j++) {
            const int col = bn + (wc * WN + j) * 16 + m0;
            if (col >= Nreal) continue;
            const float bv = bias ? bias[col] : 0.f;
            #pragma unroll
            for (int r = 0; r < 4; r++) {
                const int row = bm + (wr * WM + i) * 16 + q0 * 4 + r;
                float v = acc[i][j][r] + bv;
                if (Cadd) v += Cadd[(size_t)row * ldadd + col];
                if (col < split) {
                    if (act & 1) v = fmaxf(v, 0.f);
                    Cb[(size_t)row * ldcb + col] = f2b(v);
                } else {
                    if (act & 2) v = fmaxf(v, 0.f);
                    Cf[(size_t)row * ldcf + col - split] = v;
                }
            }
        }
    }
}

// ---------------- mega dispatch: big GEMM + 2 rider tasks -----------------
// blocks [0,1568): task0 [v_img;v_imgv] = relu([img0;img_feat]@av_W+b), 128x128x32 dbuf
// blocks [1568,1632): task1 WvWo^T = Wo^T x Wv -> wt_qkv[2M..], 128x128x32
// blocks [1632,3168): task2 q_emb(bf16)|pre_uq(fp32) = rv @ [qc|uqc_bot], 32x64x64
// R10 lesson: LDS union must stay 32KB or the host path loses co-residency
// (48KB -> 3 blocks/CU -> 150us). Rider uses BK=64 (2x6144 u16 <= 16384) so
// the union is exactly the host's 2x8192. m114: riders fill the host's idle
// issue slots (host MfmaUtil ~12%); time ~ max, not sum.
struct BT { const u16* A; int lda; const u16* Bt; const float* bias;
            u16* C; int ldc; int K; int act; int gnx; };

__global__ void __launch_bounds__(256) mega1(
    BT t0, BT t1,
    const u16* __restrict__ A2p, int lda2, const u16* __restrict__ Bt2,
    const float* __restrict__ bias2, u16* __restrict__ Cb2, float* __restrict__ Cf2)
{
    __shared__ u16 lds[16384];                    // 32KB union (both paths)
    const int tid  = threadIdx.x;
    const int wave = tid >> 6, lane = tid & 63;
    const int m0 = lane & 15, q0 = lane >> 4;

    const int nblk = gridDim.x;
    const int lid = blockIdx.x;
    const int per = nblk >> 3, rem = nblk & 7;
    const int xcd = lid & 7, slot = lid >> 3;
    const int t = xcd * per + ((xcd < rem) ? xcd : rem) + slot;

    if (t < 1632) {
        // ---- 128x128x32 dbuf path ----
        const BT T = (t < 1568) ? t0 : t1;
        const int tt = (t < 1568) ? t : t - 1568;
        const int tm = tt / T.gnx, tn = tt - tm * T.gnx;
        const int bm = tm * 128, bn = tn * 128;
        const int wr = wave >> 1, wc = wave & 1;

        auto stage = [&](int kt, int buf) {
            u16* l = &lds[buf * 8192];
            #pragma unroll
            for (int s = wave; s < 8; s += 4) {
                const u16* gp = T.A + (size_t)(bm + s * 16 + m0) * T.lda + kt + q0 * 8;
                ASYNC16(gp, &l[s * 512]);
            }
            #pragma unroll
            for (int s = wave; s < 8; s += 4) {
                const u16* gp = T.Bt + (size_t)(bn + s * 16 + m0) * T.K + kt + q0 * 8;
                ASYNC16(gp, &l[(8 + s) * 512]);
            }
        };

        f32x4 acc[4][4];
        #pragma unroll
        for (int i = 0; i < 4; i++)
            #pragma unroll
            for (int j = 0; j < 4; j++)
                acc[i][j] = (f32x4){0.f, 0.f, 0.f, 0.f};

        stage(0, 0);
        const int nIter = T.K >> 5;
        for (int it = 0; it < nIter; ++it) {
            __syncthreads();
            if (it + 1 < nIter) stage((it + 1) * 32, (it + 1) & 1);
            const u16* l = &lds[(it & 1) * 8192];
            short8 af[4], bf[4];
            #pragma unroll
            for (int i = 0; i < 4; i++)
                af[i] = *(const short8*)&l[((wr * 4 + i) * 64 + lane) * 8];
            #pragma unroll
            for (int j = 0; j < 4; j++)
                bf[j] = *(const short8*)&l[((8 + wc * 4 + j) * 64 + lane) * 8];
            #pragma unroll
            for (int i = 0; i < 4; i++)
                #pragma unroll
                for (int j = 0; j < 4; j++)
                    acc[i][j] = __builtin_amdgcn_mfma_f32_16x16x32_bf16(
                        af[i], bf[j], acc[i][j], 0, 0, 0);
        }
        // direct-store epilogue (R9's LDS epilogue regressed: +209k conflicts)
        #pragma unroll
        for (int i = 0; i < 4; i++) {
            #pragma unroll
            for (int j = 0; j < 4; j++) {
                const int col = bn + (wc * 4 + j) * 16 + m0;
                const float bv = T.bias ? T.bias[col] : 0.f;
                #pragma unroll
                for (int r = 0; r < 4; r++) {
                    const int row = bm + (wr * 4 + i) * 16 + q0 * 4 + r;
                    float v = acc[i][j][r] + bv;
                    if (T.act) v = fmaxf(v, 0.f);
                    T.C[(size_t)row * T.ldc + col] = f2b(v);
                }
            }
        }
    } else {
        // ---- 32x64x64 dbuf path: q_emb | pre_uq = rv @ [qc|uqc_bot] ----
        constexpr int BUF2 = 6144;               // (2+4)*2*512
        const int tt = t - 1632;
        const int tm = tt >> 5, tn = tt & 31;    // n-fastest, 32 n-tiles
        const int bm = tm * 32, bn = tn * 64;
        const int wr = wave >> 1, wc = wave & 1;
        const int K = 640;

        auto stage = [&](int kt, int buf) {
            u16* l = &lds[buf * BUF2];
            #pragma unroll
            for (int s = wave; s < 2; s += 4)
                #pragma unroll
                for (int g = 0; g < 2; g++) {
                    const u16* gp = A2p + (size_t)(bm + s * 16 + m0) * lda2 + kt + g * 32 + q0 * 8;
                    ASYNC16(gp, &l[(s * 2 + g) * 512]);
                }
            #pragma unroll
            for (int s = wave; s < 4; s += 4)
                #pragma unroll
                for (int g = 0; g < 2; g++) {
                    const u16* gp = Bt2 + (size_t)(bn + s * 16 + m0) * K + kt + g * 32 + q0 * 8;
                    ASYNC16(gp, &l[(4 + s * 2 + g) * 512]);
                }
        };

        f32x4 acc[2];
        acc[0] = (f32x4){0.f, 0.f, 0.f, 0.f};
        acc[1] = (f32x4){0.f, 0.f, 0.f, 0.f};

        stage(0, 0);
        const int nIter = K / 64;                // 10
        for (int it = 0; it < nIter; ++it) {
            __syncthreads();
            if (it + 1 < nIter) stage((it + 1) * 64, (it + 1) & 1);
            const u16* l = &lds[(it & 1) * BUF2];
            short8 af[2], bf[2][2];
            #pragma unroll
            for (int g = 0; g < 2; g++)
                af[g] = *(const short8*)&l[((wr * 2 + g) * 64 + lane) * 8];
            #pragma unroll
            for (int j = 0; j < 2; j++)
                #pragma unroll
                for (int g = 0; g < 2; g++)
                    bf[j][g] = *(const short8*)&l[((4 + (wc * 2 + j) * 2 + g) * 64 + lane) * 8];
            #pragma unroll
            for (int g = 0; g < 2; g++)
                #pragma unroll
                for (int j = 0; j < 2; j++)
                    acc[j] = __builtin_amdgcn_mfma_f32_16x16x32_bf16(
                        af[g], bf[j][g], acc[j], 0, 0, 0);
        }

        #pragma unroll
        for (int j = 0; j < 2; j++) {
            const int col = bn + (wc * 2 + j) * 16 + m0;
            const float bv = bias2[col];
            #pragma unroll
            for (int r = 0; r < 4; r++) {
                const int row = bm + wr * 16 + q0 * 4 + r;
                float v = acc[j][r] + bv;
                if (col < 1024) {
                    v = fmaxf(v, 0.f);                       // relu on q_emb
                    Cb2[(size_t)row * 1024 + col] = f2b(v);
                } else {
                    Cf2[(size_t)row * 1024 + col - 1024] = v; // pre_uq, no relu
                }
            }
        }
    }
}

// ---------------- unified prep kernel ----------------
struct PrepSrc { const float* s[11]; };

__global__ void __launch_bounds__(256) prep_kernel(
    PrepSrc ps, u16* __restrict__ wt,
    const float* __restrict__ verb_table, const float* __restrict__ role_table,
    const int* __restrict__ gt_verb, const int* __restrict__ role_idx,
    u16* __restrict__ cat,
    const float* __restrict__ v_org, u16* __restrict__ A1,
    const float* __restrict__ img_feat, u16* __restrict__ A2,
    const float* __restrict__ Wv,
    const float* __restrict__ aq_b, const float* __restrict__ qn_b,
    const float* __restrict__ qc_b,
    float* __restrict__ aqqn_b, float* __restrict__ qcz_b)
{
    __shared__ float sm[64 * 50];
    const int bid = blockIdx.x, tid = threadIdx.x;

    if (bid < 10496) {
        const int tStart[12] = {0,640,1152,2176,3200,3712,4736,5760,6784,7808,8448,10496};
        const int tK[11]  = {600,512,1024,1024,512,1024,1024,1024,1024,600,1024};
        const int tN[11]  = {1024,1024,1024,1024,1024,1024,1024,1024,1024,1024,2001};
        const int tKp[11] = {640,512,1024,1024,512,1024,1024,1024,1024,640,1024};
        const int tNp[11] = {1024,1024,1024,1024,1024,1024,1024,1024,1024,1024,2048};
        const long tDst[11] = {(long)O_QC,(long)O_AV,(long)O_AQQN,(long)(O_AQQN+1048576),
                               (long)O_VN,(long)O_QKV,(long)(O_QKV+1048576),
                               (long)O_WO,(long)O_UQCT,(long)O_UQCB,(long)O_CLS};
        int e = 0;
        while (bid >= tStart[e + 1]) e++;
        const int local = bid - tStart[e];
        const int ktiles = tKp[e] >> 5;
        const int bx = local % ktiles, by = local / ktiles;
        const float* W = ps.s[e];
        u16* Wt = wt + tDst[e];
        const int K = tK[e], Nn = tN[e], Kp = tKp[e], Np = tNp[e];
        const int kt = bx * 32, nt = by * 32;
        // read: float4 per thread; tile 32(k) x 32(n)
        {
            const int rowk = tid >> 3, ng = (tid & 7) * 4;
            const int k = kt + rowk;
            float4 v = {0.f, 0.f, 0.f, 0.f};
            if (k < K) {
                const int n = nt + ng;
                if (n + 3 < Nn) v = *(const float4*)(W + (size_t)k * Nn + n);
                else {
                    v.x = (n + 0 < Nn) ? W[(size_t)k * Nn + n + 0] : 0.f;
                    v.y = (n + 1 < Nn) ? W[(size_t)k * Nn + n + 1] : 0.f;
                    v.z = (n + 2 < Nn) ? W[(size_t)k * Nn + n + 2] : 0.f;
                    v.w = (n + 3 < Nn) ? W[(size_t)k * Nn + n + 3] : 0.f;
                }
            }
            sm[rowk * 33 + ng + 0] = v.x;
            sm[rowk * 33 + ng + 1] = v.y;
            sm[rowk * 33 + ng + 2] = v.z;
            sm[rowk * 33 + ng + 3] = v.w;
        }
        __syncthreads();
        // write: ushort4 per thread (4 consecutive k for one n)
        {
            const int nrow = tid >> 3, kg = (tid & 7) * 4;
            const int n = nt + nrow;
            if (n < Np) {
                ushort4 o;
                o.x = f2b(sm[(kg + 0) * 33 + nrow]);
                o.y = f2b(sm[(kg + 1) * 33 + nrow]);
                o.z = f2b(sm[(kg + 2) * 33 + nrow]);
                o.w = f2b(sm[(kg + 3) * 33 + nrow]);
                *(ushort4*)(Wt + (size_t)n * Kp + kt + kg) = o;
            }
        }
    } else if (bid < 14336) {
        const int idx = (bid - 10496) * 256 + tid;          // NN*640 exactly
        const int n = idx / 640;
        const int col = idx - n * 640;
        const int b = n / Rr, r = n - b * Rr;
        float v = 0.f;
        if (col < Ee)          v = verb_table[(size_t)gt_verb[b] * Ee + col];
        else if (col < 2 * Ee) v = role_table[(size_t)role_idx[b * Rr + r] * Ee + (col - Ee)];
        cat[(size_t)n * 1664 + 1024 + col] = f2b(v);
    } else if (bid < 16384) {
        const int local = bid - 14336;
        const int b = local >> 3, c0 = (local & 7) << 6;
        {
            const int ci = tid >> 2, k0 = tid & 3;
            const float* p = v_org + ((size_t)b * Cc + c0 + ci) * Ksp;
            for (int k = k0; k < Ksp; k += 4) sm[ci * 50 + k] = p[k];
        }
        __syncthreads();
        {
            const int cc = tid & 63, kb = tid >> 6;
            for (int k = kb; k < Ksp; k += 4)
                A1[((size_t)b * Ksp + k) * Cc + c0 + cc] = f2b(sm[cc * 50 + k]);
        }
    } else if (bid < 22656) {
        const int i = (bid - 16384) * 256 + tid;            // 12544*512/4 exactly
        const float4 v = ((const float4*)img_feat)[i];
        ushort4 o;
        o.x = f2b(v.x); o.y = f2b(v.y); o.z = f2b(v.z); o.w = f2b(v.w);
        ((ushort4*)A2)[i] = o;
    } else if (bid < 23680) {
        const int i = (bid - 22656) * 256 + tid;            // 1024*1024/4 exactly
        const float4 v = ((const float4*)Wv)[i];
        ushort4 o;
        o.x = f2b(v.x); o.y = f2b(v.y); o.z = f2b(v.z); o.w = f2b(v.w);
        ((ushort4*)(wt + O_WVP))[i] = o;
    } else {
        const int i = (bid - 23680) * 256 + tid;
        if (i < 2048)      aqqn_b[i] = (i < 1024) ? aq_b[i] : qn_b[i - 1024];
        else if (i < 4096) {
            const int k = i - 2048;
            qcz_b[k] = (k < 1024) ? qc_b[k] : 0.f;
        }
    }
}

// ---------------- batch-level fused attention (task-merged) ----------------
__global__ void __launch_bounds__(256) att_kernel(
    const u16* __restrict__ Vh0, const u16* __restrict__ Q,
    const float* __restrict__ aoW, const float* __restrict__ aoB,
    const u16* __restrict__ IMG0, u16* __restrict__ Vemb0)
{
    const int task = blockIdx.x >> 8;
    const int b = blockIdx.x & 255;
    const u16* Vh   = Vh0   + (size_t)task * 12544 * 1024;
    const u16* IMGb = IMG0  + (size_t)task * 12544 * 512;
    u16* Vemb       = Vemb0 + (size_t)task * NN * 512;
    const int tid = threadIdx.x, wave = tid >> 6, lane = tid & 63;
    __shared__ u16 s_qs[16][1032];
    __shared__ float s_log[64][6];
    __shared__ float s_att[49][6];

    for (int n = 0; n < 16; n++) {
        const u16* qp = Q + ((size_t)b * Rr + n) * Hh;
        for (int h = tid; h < 1032; h += 256) {
            u16 v = 0;
            if (n < Rr && h < Hh) v = f2b(b2f(qp[h]) * aoW[h]);
            s_qs[n][h] = v;
        }
    }
    __syncthreads();

    const int m = lane & 15, q = lane >> 4;
    {
        f32x4 acc = (f32x4){0.f, 0.f, 0.f, 0.f};
        const u16* arow = Vh + ((size_t)b * Ksp + wave * 16 + m) * Hh + q * 8;
        const u16* brow = &s_qs[m][q * 8];
        for (int kt = 0; kt < Hh; kt += 32) {
            const short8 af = *(const short8*)(arow + kt);
            const short8 bf = *(const short8*)(brow + kt);
            acc = __builtin_amdgcn_mfma_f32_16x16x32_bf16(af, bf, acc, 0, 0, 0);
        }
        const float aob = aoB[0];
        #pragma unroll
        for (int r = 0; r < 4; r++) {
            const int k = wave * 16 + q * 4 + r;   // C/D: col=lane&15, row=q*4+r
            if (k < Ksp && m < Rr) s_log[k][m] = acc[r] + aob;
        }
    }
    __syncthreads();

    if (wave == 0) {
        for (int r = 0; r < Rr; r++) {
            const float v = (lane < Ksp) ? s_log[lane][r] : -INFINITY;
            float mx = v;
            #pragma unroll
            for (int off = 32; off; off >>= 1) mx = fmaxf(mx, __shfl_down(mx, off));
            mx = __shfl(mx, 0);
            const float e = (lane < Ksp) ? expf(v - mx) : 0.f;
            float s = e;
            #pragma unroll
            for (int off = 32; off; off >>= 1) s += __shfl_down(s, off);
            s = __shfl(s, 0);
            if (lane < Ksp) s_att[lane][r] = e / s;
        }
    }
    __syncthreads();

    float acc2[Rr][2];
    #pragma unroll
    for (int r = 0; r < Rr; r++) { acc2[r][0] = 0.f; acc2[r][1] = 0.f; }
    const u16* ib = IMGb + (size_t)b * Ksp * Cc + tid * 2;
    #pragma unroll 7
    for (int k = 0; k < Ksp; k++) {
        const ushort2 v = *(const ushort2*)(ib + (size_t)k * Cc);
        const float v0 = b2f(v.x), v1 = b2f(v.y);
        #pragma unroll
        for (int r = 0; r < Rr; r++) {
            const float w = s_att[k][r];
            acc2[r][0] += w * v0; acc2[r][1] += w * v1;
        }
    }
    #pragma unroll
    for (int r = 0; r < Rr; r++) {
        ushort2 o; o.x = f2b(acc2[r][0]); o.y = f2b(acc2[r][1]);
        *(ushort2*)(Vemb + ((size_t)b * Rr + r) * Cc + tid * 2) = o;
    }
}

// ---------------- merged MFB: rows 0..NN-1 -> a0f+a0b; NN.. -> vbf ---------
__global__ void __launch_bounds__(256) mfb2_kernel(
    const float* __restrict__ q, const float* __restrict__ v,
    float* __restrict__ a0f, u16* __restrict__ a0b, float* __restrict__ vbf)
{
    const int n = blockIdx.x;
    const int qrow = (n < NN) ? n : n - NN;
    const int tid = threadIdx.x;
    __shared__ float red[4];
    float sv[4];
    float local = 0.f;
    #pragma unroll
    for (int i = 0; i < 4; i++) {
        const int h = tid + i * 256;
        const float z = q[(size_t)qrow * Hh + h] * v[(size_t)n * Hh + h];
        const float s = (z > 0.f) ? sqrtf(z) : -sqrtf(-z);
        sv[i] = s;
        local += s * s;
    }
    #pragma unroll
    for (int off = 32; off; off >>= 1) local += __shfl_down(local, off);
    if ((tid & 63) == 0) red[tid >> 6] = local;
    __syncthreads();
    const float tot = red[0] + red[1] + red[2] + red[3];
    const float inv = 1.f / fmaxf(sqrtf(tot), 1e-12f);
    #pragma unroll
    for (int i = 0; i < 4; i++) {
        const float o = sv[i] * inv;
        if (n < NN) {
            const size_t off2 = (size_t)n * Hh + tid + i * 256;
            a0f[off2] = o; a0b[off2] = f2b(o);
        } else {
            vbf[(size_t)(n - NN) * Hh + tid + i * 256] = o;
        }
    }
}

// ---------------- MFB(out2) + gate + tanh mix fused -> bf16 out_f ---------
__global__ void __launch_bounds__(256) mfb_gate_kernel(
    const float* __restrict__ q, const float* __restrict__ v,
    const float* __restrict__ ovb, const float* __restrict__ oa0,
    u16* __restrict__ outb)
{
    const int n = blockIdx.x;
    const int tid = threadIdx.x;
    __shared__ float red[4];
    float sv[4];
    float local = 0.f;
    #pragma unroll
    for (int i = 0; i < 4; i++) {
        const int h = tid + i * 256;
        const float z = q[(size_t)n * Hh + h] * v[(size_t)n * Hh + h];
        const float s = (z > 0.f) ? sqrtf(z) : -sqrtf(-z);
        sv[i] = s;
        local += s * s;
    }
    #pragma unroll
    for (int off = 32; off; off >>= 1) local += __shfl_down(local, off);
    if ((tid & 63) == 0) red[tid >> 6] = local;
    __syncthreads();
    const float tot = red[0] + red[1] + red[2] + red[3];
    const float inv = 1.f / fmaxf(sqrtf(tot), 1e-12f);
    #pragma unroll
    for (int i = 0; i < 4; i++) {
        const size_t off2 = (size_t)n * Hh + tid + i * 256;
        const float o2 = sv[i] * inv;
        const float ov = ovb[off2], a0 = oa0[off2];
        const float g = 1.f / (1.f + expf(-(o2 + ov)));
        outb[off2] = f2b((1.f - g) * ov + g * tanhf(o2 + a0));
    }
}

// ---------------- neighbor attention -> neigh (bf16, strided out) ---------
__global__ void __launch_bounds__(256) nattn_kernel(
    const u16* __restrict__ qkv, const int* __restrict__ mask,
    u16* __restrict__ outp, int ldout)
{
    const int b = blockIdx.x;
    const int tid = threadIdx.x;
    __shared__ float s_sc[Rr][Rr];
    __shared__ float s_at[Rr][Rr];
    const int wave = tid >> 6, lane = tid & 63;
    for (int p = wave; p < Rr * Rr; p += 4) {
        const int i = p / Rr, j = p - (p / Rr) * Rr;
        const u16* qp = qkv + ((size_t)(b * Rr + i)) * 3072;
        const u16* kp = qkv + ((size_t)(b * Rr + j)) * 3072 + 1024;
        float s = 0.f;
        for (int h = lane * 2; h < Hh; h += 128) {
            const ushort2 qv = *(const ushort2*)(qp + h);
            const ushort2 kv = *(const ushort2*)(kp + h);
            s += b2f(qv.x) * b2f(kv.x) + b2f(qv.y) * b2f(kv.y);
        }
        #pragma unroll
        for (int off = 32; off; off >>= 1) s += __shfl_down(s, off);
        if (lane == 0) s_sc[i][j] = s * 0.03125f;   // 1/sqrt(1024)
    }
    __syncthreads();
    if (tid < Rr) {
        const int i = tid;
        float vals[Rr];
        float m = -INFINITY;
        #pragma unroll
        for (int j = 0; j < Rr; j++) {
            const float mij = (i == j) ? 0.f : (float)mask[b * Rr * Rr + i * Rr + j];
            const float v = (mij > 0.f) ? s_sc[i][j] : -1e9f;
            vals[j] = v;
            m = fmaxf(m, v);
        }
        float ssum = 0.f;
        #pragma unroll
        for (int j = 0; j < Rr; j++) { const float e = expf(vals[j] - m); s_at[i][j] = e; ssum += e; }
        const float invs = 1.f / ssum;
        #pragma unroll
        for (int j = 0; j < Rr; j++) s_at[i][j] *= invs;
    }
    __syncthreads();
    for (int h = tid; h < Hh; h += 256) {
        #pragma unroll
        for (int i = 0; i < Rr; i++) {
            float acc = 0.f;
            #pragma unroll
            for (int j = 0; j < Rr; j++)
                acc += s_at[i][j] * b2f(qkv[((size_t)(b * Rr + j)) * 3072 + 2048 + h]);
            outp[((size_t)(b * Rr + i)) * ldout + h] = f2b(acc);
        }
    }
}

extern "C" void kernel_launch(void* const* d_in, const int* in_sizes, int n_in,
                              void* d_out, int out_size, void* d_ws, size_t ws_size,
                              hipStream_t stream)
{
    const float* v_org      = (const float*)d_in[0];
    const float* img_feat   = (const float*)d_in[1];
    const int*   gt_verb    = (const int*)d_in[2];
    const int*   role_idx   = (const int*)d_in[3];
    const int*   mask       = (const int*)d_in[4];
    const float* verb_table = (const float*)d_in[5];
    const float* role_table = (const float*)d_in[6];
    const float* qc_W  = (const float*)d_in[7];
    const float* qc_b  = (const float*)d_in[8];
    const float* av_W  = (const float*)d_in[9];
    const float* av_b  = (const float*)d_in[10];
    const float* aq_W  = (const float*)d_in[11];
    const float* aq_b  = (const float*)d_in[12];
    const float* ao_W  = (const float*)d_in[13];
    const float* ao_b  = (const float*)d_in[14];
    const float* vn_W  = (const float*)d_in[15];
    const float* vn_b  = (const float*)d_in[16];
    const float* qn_W  = (const float*)d_in[17];
    const float* qn_b  = (const float*)d_in[18];
    const float* Wq    = (const float*)d_in[19];
    const float* Wk    = (const float*)d_in[20];
    const float* Wv    = (const float*)d_in[21];
    const float* Wo    = (const float*)d_in[22];
    const float* uqc_W = (const float*)d_in[23];
    const float* uqc_b = (const float*)d_in[24];
    const float* cls_W = (const float*)d_in[25];
    const float* cls_b = (const float*)d_in[26];
    float* out = (float*)d_out;

    // ---- workspace layout ----
    char* base = (char*)d_ws;
    size_t off = 0;
    auto alloc = [&](size_t bytes) -> char* {
        char* p = base + off;
        off += (bytes + 255) & ~(size_t)255;
        return p;
    };
    u16* wt = (u16*)alloc(WT_ELEMS * 2);
    u16* A1 = (u16*)alloc((size_t)12544 * 512 * 2 * 2);        // A1|A2 contiguous
    u16* A2 = A1 + (size_t)12544 * 512;
    u16* v_img = (u16*)alloc((size_t)12544 * 1024 * 2 * 2);    // v_img|v_imgv contig
    u16* v_imgv = v_img + (size_t)12544 * 1024;
    u16* qkv = (u16*)v_imgv;                                   // reused after att
    u16* cat    = (u16*)alloc((size_t)NN * 1664 * 2);          // [neigh|rv|pad]
    u16* q_emb  = (u16*)alloc((size_t)NN * 1024 * 2);
    u16* q_att  = (u16*)alloc((size_t)NN * 1024 * 2);
    u16* uq     = (u16*)alloc((size_t)NN * 1024 * 2);
    u16* out_f  = (u16*)alloc((size_t)NN * 1024 * 2);
    u16* v_emb2 = (u16*)alloc((size_t)2 * NN * 512 * 2);
    float* v_rep2 = (float*)alloc((size_t)2 * NN * 1024 * 4);
    float* q_rep = (float*)alloc((size_t)NN * 1024 * 4);
    float* a0f   = (float*)alloc((size_t)NN * 1024 * 4);
    u16*   a0b   = (u16*)alloc((size_t)NN * 1024 * 2);
    float* vbf   = (float*)alloc((size_t)NN * 1024 * 4);
    float* pre_uq = (float*)alloc((size_t)NN * 1024 * 4);
    float* aqqn_b = (float*)alloc(2048 * 4);
    float* qcz_b  = (float*)alloc(2048 * 4);

    const dim3 blk(256);

    // 1. unified prep
    PrepSrc ps;
    ps.s[0] = qc_W; ps.s[1] = av_W; ps.s[2] = aq_W; ps.s[3] = qn_W;
    ps.s[4] = vn_W; ps.s[5] = Wq;   ps.s[6] = Wk;   ps.s[7] = Wo;
    ps.s[8] = uqc_W; ps.s[9] = uqc_W + (size_t)1024 * 1024; ps.s[10] = cls_W;
    prep_kernel<<<dim3(23696), blk, 0, stream>>>(
        ps, wt, verb_table, role_table, gt_verb, role_idx, cat,
        v_org, A1, img_feat, A2, Wv, aq_b, qn_b, qc_b, aqqn_b, qcz_b);

    // 2. mega: av-GEMM (M=25088) + WvWo rider + qc|uqc_bot rider (32KB LDS)
    BT t0 = { A1, 512, wt + O_AV, av_b, v_img, 1024, 512, 1, 8 };
    BT t1 = { wt + O_WO, 1024, wt + O_WVP, nullptr,
              wt + O_QKV + (size_t)2 * 1024 * 1024, 1024, 1024, 0, 8 };
    mega1<<<dim3(3168), blk, 0, stream>>>(t0, t1,
        cat + 1024, 1664, wt + O_QC, qcz_b, q_emb, pre_uq);

    // 3. fused: q_att(bf16,relu) | q_rep(fp32,relu) = q_emb @ [aq|qn] + b
    gemm_bf16<4,32,64,128><<<dim3(32, 48), blk, 0, stream>>>(
        q_emb, 1024, wt + O_AQQN, aqqn_b, nullptr, 0,
        q_att, 1024, q_rep, 1024, 1024, 1024, 2048, 3);
    // 4. att1 + att_v merged -> v_emb2
    att_kernel<<<dim3(512), blk, 0, stream>>>(v_img, q_att, ao_W, ao_b, A1, v_emb2);
    // 5. vn merged: v_rep2 = relu(v_emb2 @ vn + b), M=3072 (fp32)
    gemm_bf16<6,32,64,128><<<dim3(16, 96), blk, 0, stream>>>(
        v_emb2, 512, wt + O_VN, vn_b, nullptr, 0,
        nullptr, 0, v_rep2, 1024, 512, 0, 1024, 2);
    // 6. mfb merged: ans0 -> a0f/a0b; out_verb -> vbf
    mfb2_kernel<<<dim3(2 * NN), blk, 0, stream>>>(q_rep, v_rep2, a0f, a0b, vbf);
    // 7. qkv = a0 @ [Wq | Wk | WvWo]  (bf16, into v_imgv region)
    gemm_bf16<8,32,64,128><<<dim3(48, 48), blk, 0, stream>>>(
        a0b, 1024, wt + O_QKV, nullptr, nullptr, 0,
        qkv, 3072, nullptr, 0, 1024, 3072, 3072, 0);
    // 8. neighbor attention -> neigh directly into cat cols 0..1023
    nattn_kernel<<<dim3(Bb), blk, 0, stream>>>(qkv, mask, cat, 1664);
    // 9. uq = relu(neigh @ uqc_top + pre_uq + b), K=1024
    gemm_bf16<10,32,64,128><<<dim3(16, 48), blk, 0, stream>>>(
        cat, 1664, wt + O_UQCT, uqc_b, pre_uq, 1024,
        uq, 1024, nullptr, 0, 1024, 1024, 1024, 1);
    // 10. fused: q_att2 | q_rep2 = relu(uq @ [aq|qn] + b)
    gemm_bf16<11,32,64,128><<<dim3(32, 48), blk, 0, stream>>>(
        uq, 1024, wt + O_AQQN, aqqn_b, nullptr, 0,
        q_att, 1024, q_rep, 1024, 1024, 1024, 2048, 3);
    // 11. att2 (task 0 only) -> v_emb2 rows 0..NN-1
    att_kernel<<<dim3(Bb), blk, 0, stream>>>(v_img, q_att, ao_W, ao_b, A1, v_emb2);
    // 12. v_rep2[0..NN) = relu(v_emb2 @ vn + b)
    gemm_bf16<13,32,64,128><<<dim3(16, 48), blk, 0, stream>>>(
        v_emb2, 512, wt + O_VN, vn_b, nullptr, 0,
        nullptr, 0, v_rep2, 1024, 512, 0, 1024, 2);
    // 13. out2 = MFB(q_rep2, v_rep2); gate with out_verb/ans0 -> out_f
    mfb_gate_kernel<<<dim3(NN), blk, 0, stream>>>(q_rep, v_rep2, vbf, a0f, out_f);
    // 14. logits = out_f @ cls_W + b -> d_out fp32 [1536][2001]
    gemm_bf16<15,32,64,128><<<dim3(32, 48), blk, 0, stream>>>(
        out_f, 1024, wt + O_CLS, cls_b, nullptr, 0,
        nullptr, 0, out, 2001, 1024, 0, 2001, 0);
}

// Round 12
// 581.187 us; speedup vs baseline: 1.0634x; 1.0634x over previous
//
#include <hip/hip_runtime.h>
#include <math.h>

typedef unsigned short u16;
typedef __attribute__((ext_vector_type(8))) short short8;
typedef __attribute__((ext_vector_type(4))) float f32x4;

#define Bb 256
#define Rr 6
#define Ksp 49
#define Cc 512
#define Hh 1024
#define Ee 300
#define NN (Bb*Rr)        // 1536
#define NLl 2001

__device__ __forceinline__ u16 f2b(float x) {
    union { float f; unsigned u; } c; c.f = x;
    unsigned r = c.u + 0x7fffu + ((c.u >> 16) & 1u);   // RNE, finite inputs
    return (u16)(r >> 16);
}
__device__ __forceinline__ float b2f(u16 b) {
    union { unsigned u; float f; } c; c.u = ((unsigned)b) << 16; return c.f;
}

// async global->LDS, 16B per lane; LDS dest = wave-uniform base + lane*16
#define ASYNC16(gp, lp) __builtin_amdgcn_global_load_lds( \
    (const __attribute__((address_space(1))) unsigned int*)(gp), \
    (__attribute__((address_space(3))) unsigned int*)(lp), 16, 0, 0)

// ---- weight-pool element offsets (bf16 B^T buffers) ----
constexpr size_t O_QC   = 0;                            // [1024][640]
constexpr size_t O_UQCB = O_QC   + (size_t)1024*640;    // [1024][640] (uqc rows 1024..1623 ^T)
constexpr size_t O_AV   = O_UQCB + (size_t)1024*640;    // [1024][512]
constexpr size_t O_AQQN = O_AV   + (size_t)1024*512;    // [2048][1024]
constexpr size_t O_VN   = O_AQQN + (size_t)2048*1024;   // [1024][512]
constexpr size_t O_QKV  = O_VN   + (size_t)1024*512;    // [3072][1024] = Wq^T | Wk^T | WvWo^T
constexpr size_t O_WO   = O_QKV  + (size_t)3072*1024;   // [1024][1024] Wo^T
constexpr size_t O_UQCT = O_WO   + (size_t)1024*1024;   // [1024][1024] (uqc rows 0..1023 ^T)
constexpr size_t O_CLS  = O_UQCT + (size_t)1024*1024;   // [2048][1024]
constexpr size_t O_WVP  = O_CLS  + (size_t)2048*1024;   // [1024][1024] Wv plain bf16
constexpr size_t WT_ELEMS = O_WVP + (size_t)2048*1024;

// ---------------- small/medium bf16 MFMA GEMM, LDS dbuf -------------------
// TAG = instrumentation-only. A bf16 [..][lda], Bt bf16 [N][K], K % BK == 0.
// Optional fp32 addend Cadd. col<split -> Cb bf16; col>=split -> Cf fp32.
// act bit0 = relu on bf16 half, bit1 = relu on fp32 half.
template<int TAG, int BM, int BN, int BK>
__global__ void __launch_bounds__(256) gemm_bf16(
    const u16* __restrict__ A, int lda, const u16* __restrict__ Bt,
    const float* __restrict__ bias, const float* __restrict__ Cadd, int ldadd,
    u16* __restrict__ Cb, int ldcb, float* __restrict__ Cf, int ldcf,
    int K, int split, int Nreal, int act)
{
    constexpr int SM = BM / 16, SN = BN / 16;
    constexpr int KG = BK / 32;
    constexpr int WM = BM / 32, WN = BN / 32;
    constexpr int BUF = (SM + SN) * KG * 512;
    __shared__ u16 lds[2 * BUF];
    const int tid  = threadIdx.x;
    const int wave = tid >> 6, lane = tid & 63;
    const int m0 = lane & 15, q0 = lane >> 4;

    const int gn = gridDim.x;
    const int nblk = gn * gridDim.y;
    const int lid = blockIdx.y * gn + blockIdx.x;
    const int per = nblk >> 3, rem = nblk & 7;
    const int xcd = lid & 7, slot = lid >> 3;
    const int t = xcd * per + ((xcd < rem) ? xcd : rem) + slot;
    const int tm = t / gn, tn = t - tm * gn;
    const int bm = tm * BM, bn = tn * BN;
    const int wr = wave >> 1, wc = wave & 1;

    auto stage = [&](int kt, int buf) {
        u16* l = &lds[buf * BUF];
        #pragma unroll
        for (int s = wave; s < SM; s += 4)
            #pragma unroll
            for (int g = 0; g < KG; g++) {
                const u16* gp = A + (size_t)(bm + s * 16 + m0) * lda + kt + g * 32 + q0 * 8;
                ASYNC16(gp, &l[(s * KG + g) * 512]);
            }
        #pragma unroll
        for (int s = wave; s < SN; s += 4)
            #pragma unroll
            for (int g = 0; g < KG; g++) {
                const u16* gp = Bt + (size_t)(bn + s * 16 + m0) * K + kt + g * 32 + q0 * 8;
                ASYNC16(gp, &l[(SM * KG + s * KG + g) * 512]);
            }
    };

    f32x4 acc[WM][WN];
    #pragma unroll
    for (int i = 0; i < WM; i++)
        #pragma unroll
        for (int j = 0; j < WN; j++)
            acc[i][j] = (f32x4){0.f, 0.f, 0.f, 0.f};

    stage(0, 0);
    const int nIter = K / BK;
    for (int it = 0; it < nIter; ++it) {
        __syncthreads();
        if (it + 1 < nIter) stage((it + 1) * BK, (it + 1) & 1);
        const u16* l = &lds[(it & 1) * BUF];
        short8 af[WM][KG], bf[WN][KG];
        #pragma unroll
        for (int i = 0; i < WM; i++)
            #pragma unroll
            for (int g = 0; g < KG; g++)
                af[i][g] = *(const short8*)&l[(((wr * WM + i) * KG + g) * 64 + lane) * 8];
        #pragma unroll
        for (int j = 0; j < WN; j++)
            #pragma unroll
            for (int g = 0; g < KG; g++)
                bf[j][g] = *(const short8*)&l[((SM * KG + (wc * WN + j) * KG + g) * 64 + lane) * 8];
        #pragma unroll
        for (int g = 0; g < KG; g++)
            #pragma unroll
            for (int i = 0; i < WM; i++)
                #pragma unroll
                for (int j = 0; j < WN; j++)
                    acc[i][j] = __builtin_amdgcn_mfma_f32_16x16x32_bf16(
                        af[i][g], bf[j][g], acc[i][j], 0, 0, 0);
    }

    #pragma unroll
    for (int i = 0; i < WM; i++) {
        #pragma unroll
        for (int j = 0; j < WN; j++) {
            const int col = bn + (wc * WN + j) * 16 + m0;
            if (col >= Nreal) continue;
            const float bv = bias ? bias[col] : 0.f;
            #pragma unroll
            for (int r = 0; r < 4; r++) {
                const int row = bm + (wr * WM + i) * 16 + q0 * 4 + r;
                float v = acc[i][j][r] + bv;
                if (Cadd) v += Cadd[(size_t)row * ldadd + col];
                if (col < split) {
                    if (act & 1) v = fmaxf(v, 0.f);
                    Cb[(size_t)row * ldcb + col] = f2b(v);
                } else {
                    if (act & 2) v = fmaxf(v, 0.f);
                    Cf[(size_t)row * ldcf + col - split] = v;
                }
            }
        }
    }
}

// ---------------- mega dispatch: big GEMM + 2 rider tasks -----------------
// R11 lesson: task assignment must be balanced PER XCD. The R10/R11 remap
// gave XCDs 0-3 only big blocks and XCDs 5-7 only riders -> big GEMM ran on
// ~4 XCDs (150us). Fix: slot<204 -> big tile xcd*204+slot (contiguous
// M-strips per XCD preserved); slot>=204 -> rider tile xcd*192+(slot-204).
// Each XCD: 204 big + 192 rider blocks; riders fill big path's idle issue
// slots (m114: co-resident waves co-schedule, time ~ max not sum).
// grid = 8*396 = 3168 exactly. LDS union capped at 32KB (R11).
struct BT { const u16* A; int lda; const u16* Bt; const float* bias;
            u16* C; int ldc; int K; int act; int gnx; };

__global__ void __launch_bounds__(256) mega1(
    BT t0, BT t1,
    const u16* __restrict__ A2p, int lda2, const u16* __restrict__ Bt2,
    const float* __restrict__ bias2, u16* __restrict__ Cb2, float* __restrict__ Cf2)
{
    __shared__ u16 lds[16384];                    // 32KB union (both paths)
    const int tid  = threadIdx.x;
    const int wave = tid >> 6, lane = tid & 63;
    const int m0 = lane & 15, q0 = lane >> 4;

    const int lid = blockIdx.x;
    const int xcd = lid & 7, slot = lid >> 3;     // slot 0..395

    if (slot < 204) {
        // ---- big path: 128x128x32 dbuf; tile id XCD-contiguous ----
        const int tb = xcd * 204 + slot;          // 0..1631
        const BT T = (tb < 1568) ? t0 : t1;
        const int tt = (tb < 1568) ? tb : tb - 1568;
        const int tm = tt / T.gnx, tn = tt - tm * T.gnx;
        const int bm = tm * 128, bn = tn * 128;
        const int wr = wave >> 1, wc = wave & 1;

        auto stage = [&](int kt, int buf) {
            u16* l = &lds[buf * 8192];
            #pragma unroll
            for (int s = wave; s < 8; s += 4) {
                const u16* gp = T.A + (size_t)(bm + s * 16 + m0) * T.lda + kt + q0 * 8;
                ASYNC16(gp, &l[s * 512]);
            }
            #pragma unroll
            for (int s = wave; s < 8; s += 4) {
                const u16* gp = T.Bt + (size_t)(bn + s * 16 + m0) * T.K + kt + q0 * 8;
                ASYNC16(gp, &l[(8 + s) * 512]);
            }
        };

        f32x4 acc[4][4];
        #pragma unroll
        for (int i = 0; i < 4; i++)
            #pragma unroll
            for (int j = 0; j < 4; j++)
                acc[i][j] = (f32x4){0.f, 0.f, 0.f, 0.f};

        stage(0, 0);
        const int nIter = T.K >> 5;
        for (int it = 0; it < nIter; ++it) {
            __syncthreads();
            if (it + 1 < nIter) stage((it + 1) * 32, (it + 1) & 1);
            const u16* l = &lds[(it & 1) * 8192];
            short8 af[4], bf[4];
            #pragma unroll
            for (int i = 0; i < 4; i++)
                af[i] = *(const short8*)&l[((wr * 4 + i) * 64 + lane) * 8];
            #pragma unroll
            for (int j = 0; j < 4; j++)
                bf[j] = *(const short8*)&l[((8 + wc * 4 + j) * 64 + lane) * 8];
            #pragma unroll
            for (int i = 0; i < 4; i++)
                #pragma unroll
                for (int j = 0; j < 4; j++)
                    acc[i][j] = __builtin_amdgcn_mfma_f32_16x16x32_bf16(
                        af[i], bf[j], acc[i][j], 0, 0, 0);
        }
        // direct-store epilogue (R9's LDS epilogue regressed: +209k conflicts)
        #pragma unroll
        for (int i = 0; i < 4; i++) {
            #pragma unroll
            for (int j = 0; j < 4; j++) {
                const int col = bn + (wc * 4 + j) * 16 + m0;
                const float bv = T.bias ? T.bias[col] : 0.f;
                #pragma unroll
                for (int r = 0; r < 4; r++) {
                    const int row = bm + (wr * 4 + i) * 16 + q0 * 4 + r;
                    float v = acc[i][j][r] + bv;
                    if (T.act) v = fmaxf(v, 0.f);
                    T.C[(size_t)row * T.ldc + col] = f2b(v);
                }
            }
        }
    } else {
        // ---- rider: 32x64x64 dbuf; q_emb | pre_uq = rv @ [qc|uqc_bot] ----
        constexpr int BUF2 = 6144;               // (2+4)*2*512
        const int tr = xcd * 192 + (slot - 204); // 0..1535
        const int tm = tr >> 5, tn = tr & 31;    // n-fastest, 32 n-tiles
        const int bm = tm * 32, bn = tn * 64;
        const int wr = wave >> 1, wc = wave & 1;
        const int K = 640;

        auto stage = [&](int kt, int buf) {
            u16* l = &lds[buf * BUF2];
            #pragma unroll
            for (int s = wave; s < 2; s += 4)
                #pragma unroll
                for (int g = 0; g < 2; g++) {
                    const u16* gp = A2p + (size_t)(bm + s * 16 + m0) * lda2 + kt + g * 32 + q0 * 8;
                    ASYNC16(gp, &l[(s * 2 + g) * 512]);
                }
            #pragma unroll
            for (int s = wave; s < 4; s += 4)
                #pragma unroll
                for (int g = 0; g < 2; g++) {
                    const u16* gp = Bt2 + (size_t)(bn + s * 16 + m0) * K + kt + g * 32 + q0 * 8;
                    ASYNC16(gp, &l[(4 + s * 2 + g) * 512]);
                }
        };

        f32x4 acc[2];
        acc[0] = (f32x4){0.f, 0.f, 0.f, 0.f};
        acc[1] = (f32x4){0.f, 0.f, 0.f, 0.f};

        stage(0, 0);
        const int nIter = K / 64;                // 10
        for (int it = 0; it < nIter; ++it) {
            __syncthreads();
            if (it + 1 < nIter) stage((it + 1) * 64, (it + 1) & 1);
            const u16* l = &lds[(it & 1) * BUF2];
            short8 af[2], bf[2][2];
            #pragma unroll
            for (int g = 0; g < 2; g++)
                af[g] = *(const short8*)&l[((wr * 2 + g) * 64 + lane) * 8];
            #pragma unroll
            for (int j = 0; j < 2; j++)
                #pragma unroll
                for (int g = 0; g < 2; g++)
                    bf[j][g] = *(const short8*)&l[((4 + (wc * 2 + j) * 2 + g) * 64 + lane) * 8];
            #pragma unroll
            for (int g = 0; g < 2; g++)
                #pragma unroll
                for (int j = 0; j < 2; j++)
                    acc[j] = __builtin_amdgcn_mfma_f32_16x16x32_bf16(
                        af[g], bf[j][g], acc[j], 0, 0, 0);
        }

        #pragma unroll
        for (int j = 0; j < 2; j++) {
            const int col = bn + (wc * 2 + j) * 16 + m0;
            const float bv = bias2[col];
            #pragma unroll
            for (int r = 0; r < 4; r++) {
                const int row = bm + wr * 16 + q0 * 4 + r;
                float v = acc[j][r] + bv;
                if (col < 1024) {
                    v = fmaxf(v, 0.f);                       // relu on q_emb
                    Cb2[(size_t)row * 1024 + col] = f2b(v);
                } else {
                    Cf2[(size_t)row * 1024 + col - 1024] = v; // pre_uq, no relu
                }
            }
        }
    }
}

// ---------------- unified prep kernel ----------------
struct PrepSrc { const float* s[11]; };

__global__ void __launch_bounds__(256) prep_kernel(
    PrepSrc ps, u16* __restrict__ wt,
    const float* __restrict__ verb_table, const float* __restrict__ role_table,
    const int* __restrict__ gt_verb, const int* __restrict__ role_idx,
    u16* __restrict__ cat,
    const float* __restrict__ v_org, u16* __restrict__ A1,
    const float* __restrict__ img_feat, u16* __restrict__ A2,
    const float* __restrict__ Wv,
    const float* __restrict__ aq_b, const float* __restrict__ qn_b,
    const float* __restrict__ qc_b,
    float* __restrict__ aqqn_b, float* __restrict__ qcz_b)
{
    __shared__ float sm[64 * 50];
    const int bid = blockIdx.x, tid = threadIdx.x;

    if (bid < 10496) {
        const int tStart[12] = {0,640,1152,2176,3200,3712,4736,5760,6784,7808,8448,10496};
        const int tK[11]  = {600,512,1024,1024,512,1024,1024,1024,1024,600,1024};
        const int tN[11]  = {1024,1024,1024,1024,1024,1024,1024,1024,1024,1024,2001};
        const int tKp[11] = {640,512,1024,1024,512,1024,1024,1024,1024,640,1024};
        const int tNp[11] = {1024,1024,1024,1024,1024,1024,1024,1024,1024,1024,2048};
        const long tDst[11] = {(long)O_QC,(long)O_AV,(long)O_AQQN,(long)(O_AQQN+1048576),
                               (long)O_VN,(long)O_QKV,(long)(O_QKV+1048576),
                               (long)O_WO,(long)O_UQCT,(long)O_UQCB,(long)O_CLS};
        int e = 0;
        while (bid >= tStart[e + 1]) e++;
        const int local = bid - tStart[e];
        const int ktiles = tKp[e] >> 5;
        const int bx = local % ktiles, by = local / ktiles;
        const float* W = ps.s[e];
        u16* Wt = wt + tDst[e];
        const int K = tK[e], Nn = tN[e], Kp = tKp[e], Np = tNp[e];
        const int kt = bx * 32, nt = by * 32;
        // read: float4 per thread; tile 32(k) x 32(n)
        {
            const int rowk = tid >> 3, ng = (tid & 7) * 4;
            const int k = kt + rowk;
            float4 v = {0.f, 0.f, 0.f, 0.f};
            if (k < K) {
                const int n = nt + ng;
                if (n + 3 < Nn) v = *(const float4*)(W + (size_t)k * Nn + n);
                else {
                    v.x = (n + 0 < Nn) ? W[(size_t)k * Nn + n + 0] : 0.f;
                    v.y = (n + 1 < Nn) ? W[(size_t)k * Nn + n + 1] : 0.f;
                    v.z = (n + 2 < Nn) ? W[(size_t)k * Nn + n + 2] : 0.f;
                    v.w = (n + 3 < Nn) ? W[(size_t)k * Nn + n + 3] : 0.f;
                }
            }
            sm[rowk * 33 + ng + 0] = v.x;
            sm[rowk * 33 + ng + 1] = v.y;
            sm[rowk * 33 + ng + 2] = v.z;
            sm[rowk * 33 + ng + 3] = v.w;
        }
        __syncthreads();
        // write: ushort4 per thread (4 consecutive k for one n)
        {
            const int nrow = tid >> 3, kg = (tid & 7) * 4;
            const int n = nt + nrow;
            if (n < Np) {
                ushort4 o;
                o.x = f2b(sm[(kg + 0) * 33 + nrow]);
                o.y = f2b(sm[(kg + 1) * 33 + nrow]);
                o.z = f2b(sm[(kg + 2) * 33 + nrow]);
                o.w = f2b(sm[(kg + 3) * 33 + nrow]);
                *(ushort4*)(Wt + (size_t)n * Kp + kt + kg) = o;
            }
        }
    } else if (bid < 14336) {
        const int idx = (bid - 10496) * 256 + tid;          // NN*640 exactly
        const int n = idx / 640;
        const int col = idx - n * 640;
        const int b = n / Rr, r = n - b * Rr;
        float v = 0.f;
        if (col < Ee)          v = verb_table[(size_t)gt_verb[b] * Ee + col];
        else if (col < 2 * Ee) v = role_table[(size_t)role_idx[b * Rr + r] * Ee + (col - Ee)];
        cat[(size_t)n * 1664 + 1024 + col] = f2b(v);
    } else if (bid < 16384) {
        const int local = bid - 14336;
        const int b = local >> 3, c0 = (local & 7) << 6;
        {
            const int ci = tid >> 2, k0 = tid & 3;
            const float* p = v_org + ((size_t)b * Cc + c0 + ci) * Ksp;
            for (int k = k0; k < Ksp; k += 4) sm[ci * 50 + k] = p[k];
        }
        __syncthreads();
        {
            const int cc = tid & 63, kb = tid >> 6;
            for (int k = kb; k < Ksp; k += 4)
                A1[((size_t)b * Ksp + k) * Cc + c0 + cc] = f2b(sm[cc * 50 + k]);
        }
    } else if (bid < 22656) {
        const int i = (bid - 16384) * 256 + tid;            // 12544*512/4 exactly
        const float4 v = ((const float4*)img_feat)[i];
        ushort4 o;
        o.x = f2b(v.x); o.y = f2b(v.y); o.z = f2b(v.z); o.w = f2b(v.w);
        ((ushort4*)A2)[i] = o;
    } else if (bid < 23680) {
        const int i = (bid - 22656) * 256 + tid;            // 1024*1024/4 exactly
        const float4 v = ((const float4*)Wv)[i];
        ushort4 o;
        o.x = f2b(v.x); o.y = f2b(v.y); o.z = f2b(v.z); o.w = f2b(v.w);
        ((ushort4*)(wt + O_WVP))[i] = o;
    } else {
        const int i = (bid - 23680) * 256 + tid;
        if (i < 2048)      aqqn_b[i] = (i < 1024) ? aq_b[i] : qn_b[i - 1024];
        else if (i < 4096) {
            const int k = i - 2048;
            qcz_b[k] = (k < 1024) ? qc_b[k] : 0.f;
        }
    }
}

// ---------------- batch-level fused attention (task-merged) ----------------
__global__ void __launch_bounds__(256) att_kernel(
    const u16* __restrict__ Vh0, const u16* __restrict__ Q,
    const float* __restrict__ aoW, const float* __restrict__ aoB,
    const u16* __restrict__ IMG0, u16* __restrict__ Vemb0)
{
    const int task = blockIdx.x >> 8;
    const int b = blockIdx.x & 255;
    const u16* Vh   = Vh0   + (size_t)task * 12544 * 1024;
    const u16* IMGb = IMG0  + (size_t)task * 12544 * 512;
    u16* Vemb       = Vemb0 + (size_t)task * NN * 512;
    const int tid = threadIdx.x, wave = tid >> 6, lane = tid & 63;
    __shared__ u16 s_qs[16][1032];
    __shared__ float s_log[64][6];
    __shared__ float s_att[49][6];

    for (int n = 0; n < 16; n++) {
        const u16* qp = Q + ((size_t)b * Rr + n) * Hh;
        for (int h = tid; h < 1032; h += 256) {
            u16 v = 0;
            if (n < Rr && h < Hh) v = f2b(b2f(qp[h]) * aoW[h]);
            s_qs[n][h] = v;
        }
    }
    __syncthreads();

    const int m = lane & 15, q = lane >> 4;
    {
        f32x4 acc = (f32x4){0.f, 0.f, 0.f, 0.f};
        const u16* arow = Vh + ((size_t)b * Ksp + wave * 16 + m) * Hh + q * 8;
        const u16* brow = &s_qs[m][q * 8];
        for (int kt = 0; kt < Hh; kt += 32) {
            const short8 af = *(const short8*)(arow + kt);
            const short8 bf = *(const short8*)(brow + kt);
            acc = __builtin_amdgcn_mfma_f32_16x16x32_bf16(af, bf, acc, 0, 0, 0);
        }
        const float aob = aoB[0];
        #pragma unroll
        for (int r = 0; r < 4; r++) {
            const int k = wave * 16 + q * 4 + r;   // C/D: col=lane&15, row=q*4+r
            if (k < Ksp && m < Rr) s_log[k][m] = acc[r] + aob;
        }
    }
    __syncthreads();

    if (wave == 0) {
        for (int r = 0; r < Rr; r++) {
            const float v = (lane < Ksp) ? s_log[lane][r] : -INFINITY;
            float mx = v;
            #pragma unroll
            for (int off = 32; off; off >>= 1) mx = fmaxf(mx, __shfl_down(mx, off));
            mx = __shfl(mx, 0);
            const float e = (lane < Ksp) ? expf(v - mx) : 0.f;
            float s = e;
            #pragma unroll
            for (int off = 32; off; off >>= 1) s += __shfl_down(s, off);
            s = __shfl(s, 0);
            if (lane < Ksp) s_att[lane][r] = e / s;
        }
    }
    __syncthreads();

    float acc2[Rr][2];
    #pragma unroll
    for (int r = 0; r < Rr; r++) { acc2[r][0] = 0.f; acc2[r][1] = 0.f; }
    const u16* ib = IMGb + (size_t)b * Ksp * Cc + tid * 2;
    #pragma unroll 7
    for (int k = 0; k < Ksp; k++) {
        const ushort2 v = *(const ushort2*)(ib + (size_t)k * Cc);
        const float v0 = b2f(v.x), v1 = b2f(v.y);
        #pragma unroll
        for (int r = 0; r < Rr; r++) {
            const float w = s_att[k][r];
            acc2[r][0] += w * v0; acc2[r][1] += w * v1;
        }
    }
    #pragma unroll
    for (int r = 0; r < Rr; r++) {
        ushort2 o; o.x = f2b(acc2[r][0]); o.y = f2b(acc2[r][1]);
        *(ushort2*)(Vemb + ((size_t)b * Rr + r) * Cc + tid * 2) = o;
    }
}

// ---------------- merged MFB: rows 0..NN-1 -> a0f+a0b; NN.. -> vbf ---------
__global__ void __launch_bounds__(256) mfb2_kernel(
    const float* __restrict__ q, const float* __restrict__ v,
    float* __restrict__ a0f, u16* __restrict__ a0b, float* __restrict__ vbf)
{
    const int n = blockIdx.x;
    const int qrow = (n < NN) ? n : n - NN;
    const int tid = threadIdx.x;
    __shared__ float red[4];
    float sv[4];
    float local = 0.f;
    #pragma unroll
    for (int i = 0; i < 4; i++) {
        const int h = tid + i * 256;
        const float z = q[(size_t)qrow * Hh + h] * v[(size_t)n * Hh + h];
        const float s = (z > 0.f) ? sqrtf(z) : -sqrtf(-z);
        sv[i] = s;
        local += s * s;
    }
    #pragma unroll
    for (int off = 32; off; off >>= 1) local += __shfl_down(local, off);
    if ((tid & 63) == 0) red[tid >> 6] = local;
    __syncthreads();
    const float tot = red[0] + red[1] + red[2] + red[3];
    const float inv = 1.f / fmaxf(sqrtf(tot), 1e-12f);
    #pragma unroll
    for (int i = 0; i < 4; i++) {
        const float o = sv[i] * inv;
        if (n < NN) {
            const size_t off2 = (size_t)n * Hh + tid + i * 256;
            a0f[off2] = o; a0b[off2] = f2b(o);
        } else {
            vbf[(size_t)(n - NN) * Hh + tid + i * 256] = o;
        }
    }
}

// ---------------- MFB(out2) + gate + tanh mix fused -> bf16 out_f ---------
__global__ void __launch_bounds__(256) mfb_gate_kernel(
    const float* __restrict__ q, const float* __restrict__ v,
    const float* __restrict__ ovb, const float* __restrict__ oa0,
    u16* __restrict__ outb)
{
    const int n = blockIdx.x;
    const int tid = threadIdx.x;
    __shared__ float red[4];
    float sv[4];
    float local = 0.f;
    #pragma unroll
    for (int i = 0; i < 4; i++) {
        const int h = tid + i * 256;
        const float z = q[(size_t)n * Hh + h] * v[(size_t)n * Hh + h];
        const float s = (z > 0.f) ? sqrtf(z) : -sqrtf(-z);
        sv[i] = s;
        local += s * s;
    }
    #pragma unroll
    for (int off = 32; off; off >>= 1) local += __shfl_down(local, off);
    if ((tid & 63) == 0) red[tid >> 6] = local;
    __syncthreads();
    const float tot = red[0] + red[1] + red[2] + red[3];
    const float inv = 1.f / fmaxf(sqrtf(tot), 1e-12f);
    #pragma unroll
    for (int i = 0; i < 4; i++) {
        const size_t off2 = (size_t)n * Hh + tid + i * 256;
        const float o2 = sv[i] * inv;
        const float ov = ovb[off2], a0 = oa0[off2];
        const float g = 1.f / (1.f + expf(-(o2 + ov)));
        outb[off2] = f2b((1.f - g) * ov + g * tanhf(o2 + a0));
    }
}

// ---------------- neighbor attention -> neigh (bf16, strided out) ---------
__global__ void __launch_bounds__(256) nattn_kernel(
    const u16* __restrict__ qkv, const int* __restrict__ mask,
    u16* __restrict__ outp, int ldout)
{
    const int b = blockIdx.x;
    const int tid = threadIdx.x;
    __shared__ float s_sc[Rr][Rr];
    __shared__ float s_at[Rr][Rr];
    const int wave = tid >> 6, lane = tid & 63;
    for (int p = wave; p < Rr * Rr; p += 4) {
        const int i = p / Rr, j = p - (p / Rr) * Rr;
        const u16* qp = qkv + ((size_t)(b * Rr + i)) * 3072;
        const u16* kp = qkv + ((size_t)(b * Rr + j)) * 3072 + 1024;
        float s = 0.f;
        for (int h = lane * 2; h < Hh; h += 128) {
            const ushort2 qv = *(const ushort2*)(qp + h);
            const ushort2 kv = *(const ushort2*)(kp + h);
            s += b2f(qv.x) * b2f(kv.x) + b2f(qv.y) * b2f(kv.y);
        }
        #pragma unroll
        for (int off = 32; off; off >>= 1) s += __shfl_down(s, off);
        if (lane == 0) s_sc[i][j] = s * 0.03125f;   // 1/sqrt(1024)
    }
    __syncthreads();
    if (tid < Rr) {
        const int i = tid;
        float vals[Rr];
        float m = -INFINITY;
        #pragma unroll
        for (int j = 0; j < Rr; j++) {
            const float mij = (i == j) ? 0.f : (float)mask[b * Rr * Rr + i * Rr + j];
            const float v = (mij > 0.f) ? s_sc[i][j] : -1e9f;
            vals[j] = v;
            m = fmaxf(m, v);
        }
        float ssum = 0.f;
        #pragma unroll
        for (int j = 0; j < Rr; j++) { const float e = expf(vals[j] - m); s_at[i][j] = e; ssum += e; }
        const float invs = 1.f / ssum;
        #pragma unroll
        for (int j = 0; j < Rr; j++) s_at[i][j] *= invs;
    }
    __syncthreads();
    for (int h = tid; h < Hh; h += 256) {
        #pragma unroll
        for (int i = 0; i < Rr; i++) {
            float acc = 0.f;
            #pragma unroll
            for (int j = 0; j < Rr; j++)
                acc += s_at[i][j] * b2f(qkv[((size_t)(b * Rr + j)) * 3072 + 2048 + h]);
            outp[((size_t)(b * Rr + i)) * ldout + h] = f2b(acc);
        }
    }
}

extern "C" void kernel_launch(void* const* d_in, const int* in_sizes, int n_in,
                              void* d_out, int out_size, void* d_ws, size_t ws_size,
                              hipStream_t stream)
{
    const float* v_org      = (const float*)d_in[0];
    const float* img_feat   = (const float*)d_in[1];
    const int*   gt_verb    = (const int*)d_in[2];
    const int*   role_idx   = (const int*)d_in[3];
    const int*   mask       = (const int*)d_in[4];
    const float* verb_table = (const float*)d_in[5];
    const float* role_table = (const float*)d_in[6];
    const float* qc_W  = (const float*)d_in[7];
    const float* qc_b  = (const float*)d_in[8];
    const float* av_W  = (const float*)d_in[9];
    const float* av_b  = (const float*)d_in[10];
    const float* aq_W  = (const float*)d_in[11];
    const float* aq_b  = (const float*)d_in[12];
    const float* ao_W  = (const float*)d_in[13];
    const float* ao_b  = (const float*)d_in[14];
    const float* vn_W  = (const float*)d_in[15];
    const float* vn_b  = (const float*)d_in[16];
    const float* qn_W  = (const float*)d_in[17];
    const float* qn_b  = (const float*)d_in[18];
    const float* Wq    = (const float*)d_in[19];
    const float* Wk    = (const float*)d_in[20];
    const float* Wv    = (const float*)d_in[21];
    const float* Wo    = (const float*)d_in[22];
    const float* uqc_W = (const float*)d_in[23];
    const float* uqc_b = (const float*)d_in[24];
    const float* cls_W = (const float*)d_in[25];
    const float* cls_b = (const float*)d_in[26];
    float* out = (float*)d_out;

    // ---- workspace layout ----
    char* base = (char*)d_ws;
    size_t off = 0;
    auto alloc = [&](size_t bytes) -> char* {
        char* p = base + off;
        off += (bytes + 255) & ~(size_t)255;
        return p;
    };
    u16* wt = (u16*)alloc(WT_ELEMS * 2);
    u16* A1 = (u16*)alloc((size_t)12544 * 512 * 2 * 2);        // A1|A2 contiguous
    u16* A2 = A1 + (size_t)12544 * 512;
    u16* v_img = (u16*)alloc((size_t)12544 * 1024 * 2 * 2);    // v_img|v_imgv contig
    u16* v_imgv = v_img + (size_t)12544 * 1024;
    u16* qkv = (u16*)v_imgv;                                   // reused after att
    u16* cat    = (u16*)alloc((size_t)NN * 1664 * 2);          // [neigh|rv|pad]
    u16* q_emb  = (u16*)alloc((size_t)NN * 1024 * 2);
    u16* q_att  = (u16*)alloc((size_t)NN * 1024 * 2);
    u16* uq     = (u16*)alloc((size_t)NN * 1024 * 2);
    u16* out_f  = (u16*)alloc((size_t)NN * 1024 * 2);
    u16* v_emb2 = (u16*)alloc((size_t)2 * NN * 512 * 2);
    float* v_rep2 = (float*)alloc((size_t)2 * NN * 1024 * 4);
    float* q_rep = (float*)alloc((size_t)NN * 1024 * 4);
    float* a0f   = (float*)alloc((size_t)NN * 1024 * 4);
    u16*   a0b   = (u16*)alloc((size_t)NN * 1024 * 2);
    float* vbf   = (float*)alloc((size_t)NN * 1024 * 4);
    float* pre_uq = (float*)alloc((size_t)NN * 1024 * 4);
    float* aqqn_b = (float*)alloc(2048 * 4);
    float* qcz_b  = (float*)alloc(2048 * 4);

    const dim3 blk(256);

    // 1. unified prep
    PrepSrc ps;
    ps.s[0] = qc_W; ps.s[1] = av_W; ps.s[2] = aq_W; ps.s[3] = qn_W;
    ps.s[4] = vn_W; ps.s[5] = Wq;   ps.s[6] = Wk;   ps.s[7] = Wo;
    ps.s[8] = uqc_W; ps.s[9] = uqc_W + (size_t)1024 * 1024; ps.s[10] = cls_W;
    prep_kernel<<<dim3(23696), blk, 0, stream>>>(
        ps, wt, verb_table, role_table, gt_verb, role_idx, cat,
        v_org, A1, img_feat, A2, Wv, aq_b, qn_b, qc_b, aqqn_b, qcz_b);

    // 2. mega: av-GEMM + WvWo rider + qc|uqc_bot rider, per-XCD balanced
    BT t0 = { A1, 512, wt + O_AV, av_b, v_img, 1024, 512, 1, 8 };
    BT t1 = { wt + O_WO, 1024, wt + O_WVP, nullptr,
              wt + O_QKV + (size_t)2 * 1024 * 1024, 1024, 1024, 0, 8 };
    mega1<<<dim3(3168), blk, 0, stream>>>(t0, t1,
        cat + 1024, 1664, wt + O_QC, qcz_b, q_emb, pre_uq);

    // 3. fused: q_att(bf16,relu) | q_rep(fp32,relu) = q_emb @ [aq|qn] + b
    gemm_bf16<4,32,64,128><<<dim3(32, 48), blk, 0, stream>>>(
        q_emb, 1024, wt + O_AQQN, aqqn_b, nullptr, 0,
        q_att, 1024, q_rep, 1024, 1024, 1024, 2048, 3);
    // 4. att1 + att_v merged -> v_emb2
    att_kernel<<<dim3(512), blk, 0, stream>>>(v_img, q_att, ao_W, ao_b, A1, v_emb2);
    // 5. vn merged: v_rep2 = relu(v_emb2 @ vn + b), M=3072 (fp32)
    gemm_bf16<6,32,64,128><<<dim3(16, 96), blk, 0, stream>>>(
        v_emb2, 512, wt + O_VN, vn_b, nullptr, 0,
        nullptr, 0, v_rep2, 1024, 512, 0, 1024, 2);
    // 6. mfb merged: ans0 -> a0f/a0b; out_verb -> vbf
    mfb2_kernel<<<dim3(2 * NN), blk, 0, stream>>>(q_rep, v_rep2, a0f, a0b, vbf);
    // 7. qkv = a0 @ [Wq | Wk | WvWo]  (bf16, into v_imgv region)
    gemm_bf16<8,32,64,128><<<dim3(48, 48), blk, 0, stream>>>(
        a0b, 1024, wt + O_QKV, nullptr, nullptr, 0,
        qkv, 3072, nullptr, 0, 1024, 3072, 3072, 0);
    // 8. neighbor attention -> neigh directly into cat cols 0..1023
    nattn_kernel<<<dim3(Bb), blk, 0, stream>>>(qkv, mask, cat, 1664);
    // 9. uq = relu(neigh @ uqc_top + pre_uq + b), K=1024
    gemm_bf16<10,32,64,128><<<dim3(16, 48), blk, 0, stream>>>(
        cat, 1664, wt + O_UQCT, uqc_b, pre_uq, 1024,
        uq, 1024, nullptr, 0, 1024, 1024, 1024, 1);
    // 10. fused: q_att2 | q_rep2 = relu(uq @ [aq|qn] + b)
    gemm_bf16<11,32,64,128><<<dim3(32, 48), blk, 0, stream>>>(
        uq, 1024, wt + O_AQQN, aqqn_b, nullptr, 0,
        q_att, 1024, q_rep, 1024, 1024, 1024, 2048, 3);
    // 11. att2 (task 0 only) -> v_emb2 rows 0..NN-1
    att_kernel<<<dim3(Bb), blk, 0, stream>>>(v_img, q_att, ao_W, ao_b, A1, v_emb2);
    // 12. v_rep2[0..NN) = relu(v_emb2 @ vn + b)
    gemm_bf16<13,32,64,128><<<dim3(16, 48), blk, 0, stream>>>(
        v_emb2, 512, wt + O_VN, vn_b, nullptr, 0,
        nullptr, 0, v_rep2, 1024, 512, 0, 1024, 2);
    // 13. out2 = MFB(q_rep2, v_rep2); gate with out_verb/ans0 -> out_f
    mfb_gate_kernel<<<dim3(NN), blk, 0, stream>>>(q_rep, v_rep2, vbf, a0f, out_f);
    // 14. logits = out_f @ cls_W + b -> d_out fp32 [1536][2001]
    gemm_bf16<15,32,64,128><<<dim3(32, 48), blk, 0, stream>>>(
        out_f, 1024, wt + O_CLS, cls_b, nullptr, 0,
        nullptr, 0, out, 2001, 1024, 0, 2001, 0);
}